// Round 1
// 132.141 us; speedup vs baseline: 1.5291x; 1.5291x over previous
//
#include <hip/hip_runtime.h>

#define NPIX 4096
#define NT 1024
#define PPT (NPIX / NT)   // 4 per thread
#define EMPTY 0xFFFFFFFFu
#define FLAGMAGIC 0x00C0FFEEu

__global__ void ph_zero_kernel(float* out) { out[0] = 0.0f; }

__device__ __forceinline__ float kval(unsigned k) {
  unsigned u = (k & 0x80000000u) ? (k & 0x7FFFFFFFu) : ~k;
  return __uint_as_float(u);
}

__device__ __forceinline__ void memfence_compiler() {
  __asm__ volatile("" ::: "memory");
  __builtin_amdgcn_sched_barrier(0);
}

__global__ __launch_bounds__(NT) void ph_pass_kernel(const float* __restrict__ x,
                                                     float* __restrict__ out,
                                                     unsigned long long* __restrict__ ws64,
                                                     int use_ws) {
  // One 64 KB pool, phase-aliased:
  //  [0,32K)  : hash (hkey 16K | hval 16K) -> edge sort buffers -> sorted edges
  //  [32K,48K): key32 u32[4096]            -> clobbered by node records
  //  [48K,56K): label u16[4096]            -> clobbered by node records
  //  [32K,64K): node u64[4096] = creatorKey<<32 | parent   (Kruskal phase)
  __shared__ unsigned long long pool[2 * NPIX];
  __shared__ unsigned long long sbuf2[NPIX];   // 32 KB ping-pong B for the 4096 sort
  __shared__ unsigned long long wred[32];  // wave staging: [0..15] raw, [16..31] scanned
  __shared__ unsigned short blist[2048];   // basin-min pixel list (max 2048, 4-conn)
  __shared__ unsigned claim[NPIX];         // 16 KB: seq-tagged claim cells (no reset)
  __shared__ int s_chg[13];                // per-round convergence flags

  unsigned long long* sbuf = pool;
  unsigned* hkey = (unsigned*)pool;
  unsigned* hval = hkey + NPIX;
  unsigned* key32 = (unsigned*)(pool + NPIX);
  unsigned short* label = (unsigned short*)(pool + NPIX + NPIX / 2);
  unsigned long long* node = pool + NPIX;

  const int blk = blockIdx.x;            // 24 blocks: b(4) x c(3) x pass(2)
  const int b = blk / 6;
  const int rem = blk % 6;
  const int c = (rem >> 1) + 1;          // classes 1..3
  const int pass = rem & 1;              // 0 = sublevel 8-conn (H0), 1 = superlevel 4-conn (H1)
  const float* img = x + (size_t)(b * 4 + c) * NPIX;
  const int tid = threadIdx.x;
  const int lane = tid & 63, wid = tid >> 6;
  const int ndirs = pass ? 4 : 8;
  const int drr[8] = {-1, 1, 0, 0, -1, -1, 1, 1};
  const int dcc[8] = { 0, 0,-1, 1, -1,  1, -1, 1};

  // --- phase 1: monotone keys (pass 1 negates); hash+claim init folded; min ---
  if (tid < 13) s_chg[tid] = 0;
  unsigned lmin = EMPTY;
  for (int i = tid; i < NPIX; i += NT) {
    float f = img[i];
    if (pass) f = -f;
    unsigned u = __float_as_uint(f);
    unsigned k = (u & 0x80000000u) ? ~u : (u | 0x80000000u);
    key32[i] = k;
    pool[i] = ~0ull;                     // hkey/hval = EMPTY (region [0,32K))
    claim[i] = 0;
    lmin = min(lmin, k);
  }
  for (int off = 32; off > 0; off >>= 1)
    lmin = min(lmin, (unsigned)__shfl_xor((int)lmin, off));
  if (lane == 0) wred[wid] = lmin;
  __syncthreads();
  unsigned vmink = (unsigned)wred[0];
  #pragma unroll
  for (int w = 1; w < 16; w++) vmink = min(vmink, (unsigned)wred[w]);

  // --- phase 2: watershed pointers + converging pointer jumping ---
  for (int i = tid; i < NPIX; i += NT) {
    unsigned long long best = ((unsigned long long)key32[i] << 32) | (unsigned)i;
    int bestnb = i;
    int r = i >> 6, cc = i & 63;
    for (int d = 0; d < ndirs; d++) {
      int rr = r + drr[d], c2 = cc + dcc[d];
      if ((unsigned)rr >= 64u || (unsigned)c2 >= 64u) continue;
      int nb = (rr << 6) | c2;
      unsigned long long pn = ((unsigned long long)key32[nb] << 32) | (unsigned)nb;
      if (pn < best) { best = pn; bestnb = nb; }
    }
    label[i] = (unsigned short)bestnb;
  }
  __syncthreads();
  for (int round = 0; round < 12; round++) {   // >= doubling per round; early exit
    bool changed = false;
    for (int i = tid; i < NPIX; i += NT) {
      unsigned short l = label[i];
      unsigned short l2 = label[l];
      if (l2 != l) { label[i] = l2; changed = true; }
    }
    if (changed) s_chg[round] = 1;
    __syncthreads();
    if (!s_chg[round]) break;                  // block-uniform
  }

  // --- phase 3: inter-basin edges deduped to min weight per basin pair ---
  const int pdr[4] = {1, 0, 1,  1};
  const int pdc[4] = {0, 1, 1, -1};
  const int npd = pass ? 2 : 4;
  for (int i = tid; i < NPIX; i += NT) {
    int r = i >> 6, cc = i & 63;
    unsigned la = label[i];
    unsigned ki = key32[i];
    for (int d = 0; d < npd; d++) {
      int rr = r + pdr[d], c2 = cc + pdc[d];
      if ((unsigned)rr >= 64u || (unsigned)c2 >= 64u) continue;
      int nb = (rr << 6) | c2;
      unsigned lb = label[nb];
      if (lb == la) continue;
      unsigned wkey = max(ki, key32[nb]);      // weight = max endpoint key
      unsigned pk = la < lb ? ((la << 12) | lb) : ((lb << 12) | la);
      unsigned h = (pk * 2654435761u) >> 20;
      while (true) {
        unsigned old = atomicCAS(&hkey[h], EMPTY, pk);
        if (old == EMPTY || old == pk) { atomicMin(&hval[h], wkey); break; }
        h = (h + 1) & (NPIX - 1);
      }
    }
  }
  __syncthreads();

  // --- phase 4: stage hash+keys+basin flags; ONE packed u64 scan (edges|basins);
  //     write edges, basin list, node records ---
  unsigned long long item[PPT];
  unsigned mykeys[PPT];
  int cnt = 0, bcnt = 0, bmask = 0;
  #pragma unroll
  for (int q = 0; q < PPT; q++) {
    int s = tid * PPT + q;
    unsigned pk = hkey[s];
    if (pk != EMPTY) item[cnt++] = (((unsigned long long)hval[s]) << 32) | pk;
  }
  #pragma unroll
  for (int t = 0; t < PPT; t++) {
    int i = tid + t * NT;
    mykeys[t] = key32[i];
    if (label[i] == (unsigned short)i) { bmask |= 1 << t; bcnt++; }
  }
  __syncthreads();                       // all reads of pool[0..56K) done
  unsigned long long inc2 = ((unsigned long long)cnt << 32) | (unsigned)bcnt;
  for (int off = 1; off < 64; off <<= 1) {   // intra-wave inclusive scan (both counts)
    unsigned long long v = __shfl_up(inc2, off);
    if (lane >= off) inc2 += v;
  }
  if (lane == 63) wred[wid] = inc2;
  __syncthreads();
  if (wid == 0) {                        // scan the 16 wave totals in wave 0
    unsigned long long wv = (lane < 16) ? wred[lane] : 0ull;
    for (int off = 1; off < 16; off <<= 1) {
      unsigned long long v = __shfl_up(wv, off);
      if (lane >= off) wv += v;
    }
    if (lane < 16) wred[16 + lane] = wv;
  }
  __syncthreads();
  const unsigned long long tot = wred[31];
  const int M = (int)(tot >> 32);
  const int NB = (int)(tot & 0xFFFFFFFFull);
  const unsigned long long wbase = (wid == 0) ? 0ull : wred[16 + wid - 1];
  const int base = (int)((wbase >> 32) + (inc2 >> 32)) - cnt;
  int bbase = (int)((wbase & 0xFFFFFFFFull) + (inc2 & 0xFFFFFFFFull)) - bcnt;
  __syncthreads();                       // wred consumed; pool writable
  for (int q = 0; q < cnt; q++) sbuf[base + q] = item[q];
  #pragma unroll
  for (int t = 0; t < PPT; t++) {
    int i = tid + t * NT;
    node[i] = (((unsigned long long)mykeys[t]) << 32) | (unsigned)i;  // singleton
    if (bmask & (1 << t)) blist[bbase++] = (unsigned short)i;
  }
  for (int i = M + tid; i < NPIX; i += NT) sbuf[i] = ~0ull;           // pad
  __syncthreads();

  // --- phase 5: sort edges ascending by weight key ---
  if (M <= 2048) {
    // Hybrid bitonic on 2048: j<64 via shfl_xor (no barrier); j in [64,512] via
    // ping-pong LDS (A=pool[0..2048), B=pool[2048..4096)); j=1024 in-thread.
    unsigned long long v0 = sbuf[tid];
    unsigned long long v1 = sbuf[tid + 1024];
    const int i0 = tid, i1 = tid + 1024;
    auto regstage = [&](int k, int j) {
      unsigned long long p0 = __shfl_xor(v0, j);
      unsigned long long p1 = __shfl_xor(v1, j);
      bool m0 = (((i0 & j) == 0) == ((i0 & k) == 0));
      bool m1 = (((i1 & j) == 0) == ((i1 & k) == 0));
      v0 = m0 ? (v0 < p0 ? v0 : p0) : (v0 > p0 ? v0 : p0);
      v1 = m1 ? (v1 < p1 ? v1 : p1) : (v1 > p1 ? v1 : p1);
    };
    int buf = 1;
    for (int k = 2; k <= 64; k <<= 1)
      for (int j = k >> 1; j >= 1; j >>= 1) regstage(k, j);
    for (int k = 128; k <= 2048; k <<= 1) {
      for (int j = k >> 1; j >= 64; j >>= 1) {
        if (j == 1024) {                 // partner is own other element; ascending
          if (v0 > v1) { unsigned long long t = v0; v0 = v1; v1 = t; }
        } else {
          unsigned long long* bp = pool + (buf ? 2048 : 0);
          bp[tid] = v0; bp[tid + 1024] = v1;
          __syncthreads();
          unsigned long long p0 = bp[tid ^ j];
          unsigned long long p1 = bp[(tid ^ j) + 1024];
          bool m0 = (((i0 & j) == 0) == ((i0 & k) == 0));
          bool m1 = (((i1 & j) == 0) == ((i1 & k) == 0));
          v0 = m0 ? (v0 < p0 ? v0 : p0) : (v0 > p0 ? v0 : p0);
          v1 = m1 ? (v1 < p1 ? v1 : p1) : (v1 > p1 ? v1 : p1);
          buf ^= 1;
        }
      }
      for (int j = 32; j >= 1; j >>= 1) regstage(k, j);
    }
    sbuf[tid] = v0; sbuf[tid + 1024] = v1;   // final: back to A for Kruskal
    __syncthreads();
  } else {
    // 4-elem/thread hybrid bitonic on all 4096 slots (4-conn pass can have
    // M in (2048,4096]): j<64 via shfl_xor; j in [64,512] via ping-pong LDS
    // (A=sbuf, B=sbuf2); j=1024/2048 in-thread. 18 LDS barrier stages vs the
    // old in-place fallback's 78.
    unsigned long long v0 = sbuf[tid];
    unsigned long long v1 = sbuf[tid + 1024];
    unsigned long long v2 = sbuf[tid + 2048];
    unsigned long long v3 = sbuf[tid + 3072];
    const int i0 = tid, i1 = tid + 1024, i2 = tid + 2048, i3 = tid + 3072;
    auto regstage4 = [&](int k, int j) {
      unsigned long long p0 = __shfl_xor(v0, j), p1 = __shfl_xor(v1, j);
      unsigned long long p2 = __shfl_xor(v2, j), p3 = __shfl_xor(v3, j);
      bool m0 = (((i0 & j) == 0) == ((i0 & k) == 0));
      bool m1 = (((i1 & j) == 0) == ((i1 & k) == 0));
      bool m2 = (((i2 & j) == 0) == ((i2 & k) == 0));
      bool m3 = (((i3 & j) == 0) == ((i3 & k) == 0));
      v0 = m0 ? (v0 < p0 ? v0 : p0) : (v0 > p0 ? v0 : p0);
      v1 = m1 ? (v1 < p1 ? v1 : p1) : (v1 > p1 ? v1 : p1);
      v2 = m2 ? (v2 < p2 ? v2 : p2) : (v2 > p2 ? v2 : p2);
      v3 = m3 ? (v3 < p3 ? v3 : p3) : (v3 > p3 ? v3 : p3);
    };
    auto ce2 = [&](unsigned long long &a, unsigned long long &bb2, int ia, int k) {
      bool up = ((ia & k) == 0);
      if ((a > bb2) == up) { unsigned long long t = a; a = bb2; bb2 = t; }
    };
    int buf = 1;
    auto ldsstage = [&](int k, int j) {
      unsigned long long* bp = buf ? sbuf2 : sbuf;
      bp[i0] = v0; bp[i1] = v1; bp[i2] = v2; bp[i3] = v3;
      __syncthreads();
      const int pt = tid ^ j;
      unsigned long long p0 = bp[pt], p1 = bp[pt + 1024];
      unsigned long long p2 = bp[pt + 2048], p3 = bp[pt + 3072];
      bool m0 = (((i0 & j) == 0) == ((i0 & k) == 0));
      bool m1 = (((i1 & j) == 0) == ((i1 & k) == 0));
      bool m2 = (((i2 & j) == 0) == ((i2 & k) == 0));
      bool m3 = (((i3 & j) == 0) == ((i3 & k) == 0));
      v0 = m0 ? (v0 < p0 ? v0 : p0) : (v0 > p0 ? v0 : p0);
      v1 = m1 ? (v1 < p1 ? v1 : p1) : (v1 > p1 ? v1 : p1);
      v2 = m2 ? (v2 < p2 ? v2 : p2) : (v2 > p2 ? v2 : p2);
      v3 = m3 ? (v3 < p3 ? v3 : p3) : (v3 > p3 ? v3 : p3);
      buf ^= 1;
    };
    for (int k = 2; k <= 64; k <<= 1)
      for (int j = k >> 1; j >= 1; j >>= 1) regstage4(k, j);
    for (int k = 128; k <= 4096; k <<= 1) {
      if (k == 4096) { ce2(v0, v2, i0, k); ce2(v1, v3, i1, k); }   // j = 2048
      if (k >= 2048) { ce2(v0, v1, i0, k); ce2(v2, v3, i2, k); }   // j = 1024
      for (int j = 512; j >= 64; j >>= 1) if (j < k) ldsstage(k, j);
      for (int j = 32; j >= 1; j >>= 1) regstage4(k, j);
    }
    __syncthreads();                     // last ldsstage readers done before A overwrite
    sbuf[i0] = v0; sbuf[i1] = v1; sbuf[i2] = v2; sbuf[i3] = v3;
    __syncthreads();
  }

  // --- phase 6: wave-parallel Kruskal (wave 0), YOUNG-only claims.
  //     A commit writes only node[young]; two in-flight unions conflict iff
  //     they share the same young root (a root dies exactly once). Sharing an
  //     ELDER commutes: pair = (creator(young), w) regardless, and linking
  //     young -> stale-elder is transitively correct (stale elder's chain
  //     reaches the true root; creator(trueRoot) <= creator(staleElder) <
  //     creator(young) keeps young-ness consistent). Young-links strictly
  //     decrease the creator record, so the forest stays acyclic. Regions are
  //     still compiler-fenced so winners' node[] stores precede losers'
  //     re-find loads in program order. Basin-only flatten every 512 edges. ---
  double sumsq = 0.0;
  float maxp = 0.0f;
  int pcnt = 0;
  unsigned seq = 0;                      // monotone claim tag (no claim resets)
  const int ngroups = (M + 511) >> 9;
  for (int g = 0; g < ngroups; g++) {
    if (wid == 0) {
      for (int bb = 0; bb < 8; bb++) {
        const int e0 = (g << 9) + (bb << 6);
        if (e0 >= M) break;              // wave-uniform
        const int j = e0 + lane;
        const bool act = (j < M);
        unsigned long long e = act ? sbuf[j] : ~0ull;
        const unsigned wk = (unsigned)(e >> 32);
        const unsigned pk = (unsigned)(e & 0xFFFFFFu);
        unsigned xa = 0, xb = 0;
        unsigned long long recA = 0, recB = 0;
        bool pending = false;
        if (act) {
          xa = pk >> 12; xb = pk & 0xFFFu;
          recA = node[xa];
          recB = node[xb];               // finds' loads overlap across lanes
          while ((unsigned)recA != xa) { xa = (unsigned)recA; recA = node[xa]; }
          while ((unsigned)recB != xb) { xb = (unsigned)recB; recB = node[xb]; }
          pending = (xa != xb);
        }
        while (__ballot(pending)) {
          seq++;
          const unsigned myval = (seq << 6) | (63u - (unsigned)lane);
          unsigned t_elder = 0, t_young = 0;
          unsigned long long t_yrec = 0;
          // region 1: claim the young root only (smaller lane = earlier edge)
          if (pending) {
            if (recA < recB) { t_elder = xa; t_young = xb; t_yrec = recB; }
            else             { t_elder = xb; t_young = xa; t_yrec = recA; }
            atomicMax(&claim[t_young], myval);
          }
          memfence_compiler();
          // region 2: winner test (reads see ALL lanes' claims: lockstep order)
          bool winner = false;
          if (pending) winner = (claim[t_young] == myval);
          memfence_compiler();
          // region 3: commits (winners have pairwise-distinct youngs)
          if (winner) {
            const unsigned ky = (unsigned)(t_yrec >> 32);
            if (wk > ky) {               // strictly positive persistence
              float pers = kval(wk) - kval(ky);
              sumsq += (double)pers * (double)pers;
              maxp = fmaxf(maxp, pers);
              pcnt++;
            }
            node[t_young] = (t_yrec & 0xFFFFFFFF00000000ull) | t_elder;
            pending = false;
          }
          memfence_compiler();
          // region 4: losers re-find AFTER all commits of this round
          if (pending) {
            recA = node[xa]; recB = node[xb];
            while ((unsigned)recA != xa) { xa = (unsigned)recA; recA = node[xa]; }
            while ((unsigned)recB != xb) { xb = (unsigned)recB; recB = node[xb]; }
            pending = (xa != xb);
          }
        }
      }
    }
    __syncthreads();
    for (int i = tid; i < NB; i += NT) {     // flatten basins only (NB <= 2048)
      const int p0 = blist[i];
      unsigned long long rec = node[p0];
      unsigned px = (unsigned)rec;
      if (px == (unsigned)p0) continue;
      unsigned long long r2 = node[px];
      while ((unsigned)r2 != px) { px = (unsigned)r2; r2 = node[px]; }
      node[p0] = (rec & 0xFFFFFFFF00000000ull) | px;
    }
    __syncthreads();
  }
  if (wid == 0) {                        // reduce lane accumulators to lane 0
    for (int off = 32; off > 0; off >>= 1) {
      sumsq += __shfl_xor(sumsq, off);
      maxp = fmaxf(maxp, __shfl_xor(maxp, off));
      pcnt += __shfl_xor(pcnt, off);
    }
  }

  // --- phase 7: per-block contribution ---
  float contrib = 0.0f;
  if (tid == 0) {
    if (pass == 0) {
      const int nf0 = (c == 3) ? 2 : 1;      // TOPO H0: c1->1, c2->1, c3->2
      float vmin = kval(vmink);              // essential birth = global min
      if (nf0 == 1) {
        contrib = vmin * vmin + (float)sumsq;
      } else if (pcnt >= 1) {
        contrib = vmin * vmin + (1.0f - maxp) * (1.0f - maxp)
                + (float)(sumsq - (double)maxp * (double)maxp);
      } else {
        contrib = vmin * vmin + 1.0f;
      }
    } else {
      const int nf1 = (c == 2) ? 1 : 0;      // TOPO H1: c1->0, c2->1, c3->0
      if (nf1 == 0) contrib = (float)sumsq;
      else contrib = (pcnt >= 1)
        ? ((1.0f - maxp) * (1.0f - maxp) + (float)(sumsq - (double)maxp * (double)maxp))
        : 1.0f;
    }
    contrib *= 0.25f;                        // / B, B = 4
    if (use_ws) {
      // publish (value<<32 | magic) in one device-scope atomic — no fence needed
      atomicExch(&ws64[blk],
                 (((unsigned long long)__float_as_uint(contrib)) << 32) | FLAGMAGIC);
    } else {
      atomicAdd(out, contrib);               // out pre-zeroed by ph_zero_kernel
    }
  }
  // --- block 0 wave 0: gather all 24 contributions, write out ---
  if (use_ws && blk == 0 && wid == 0) {
    float v = 0.0f;
    if (lane < 24) {
      while (true) {
        unsigned long long r = atomicAdd(&ws64[lane], 0ull);  // device-coherent read
        if ((unsigned)r == FLAGMAGIC) { v = __uint_as_float((unsigned)(r >> 32)); break; }
      }
    }
    for (int off = 32; off > 0; off >>= 1) v += __shfl_xor(v, off);
    if (lane == 0) out[0] = v;
  }
}

extern "C" void kernel_launch(void* const* d_in, const int* in_sizes, int n_in,
                              void* d_out, int out_size, void* d_ws, size_t ws_size,
                              hipStream_t stream) {
  const float* x = (const float*)d_in[0];
  float* out = (float*)d_out;
  if (ws_size >= 24 * sizeof(unsigned long long)) {
    ph_pass_kernel<<<24, NT, 0, stream>>>(x, out, (unsigned long long*)d_ws, 1);
  } else {
    ph_zero_kernel<<<1, 1, 0, stream>>>(out);
    ph_pass_kernel<<<24, NT, 0, stream>>>(x, out, nullptr, 0);
  }
}

// Round 3
// 113.427 us; speedup vs baseline: 1.7814x; 1.1650x over previous
//
#include <hip/hip_runtime.h>

#define NPIX 4096
#define NT 1024
#define PPT (NPIX / NT)   // 4 per thread
#define EMPTY 0xFFFFFFFFu
#define FLAGMAGIC 0x00C0FFEEu

__global__ void ph_zero_kernel(float* out) { out[0] = 0.0f; }

__device__ __forceinline__ float kval(unsigned k) {
  unsigned u = (k & 0x80000000u) ? (k & 0x7FFFFFFFu) : ~k;
  return __uint_as_float(u);
}

__global__ __launch_bounds__(NT) void ph_pass_kernel(const float* __restrict__ x,
                                                     float* __restrict__ out,
                                                     unsigned long long* __restrict__ ws64,
                                                     int use_ws) {
  // One 64 KB pool, phase-aliased:
  //  [0,32K)  : hash (hkey 16K | hval 16K) -> edge sort buffers -> sorted edges
  //  [32K,48K): key32 u32[4096]            -> clobbered by node records
  //  [48K,56K): label u16[4096]            -> clobbered by node records
  //  [32K,64K): node u64[4096] = creatorKey<<32 | parent   (Kruskal phase)
  __shared__ unsigned long long pool[2 * NPIX];
  __shared__ unsigned long long sbuf2[NPIX];   // 32 KB ping-pong B for the 4096 sort
  __shared__ unsigned long long wred[32];  // wave staging: [0..15] raw, [16..31] scanned
  __shared__ unsigned short blist[2048];   // basin-min pixel list (max 2048, 4-conn)
  __shared__ unsigned claim[NPIX];         // 16 KB: seq-tagged claim cells (no reset)
  __shared__ int s_chg[13];                // per-round convergence flags
  __shared__ int s_flag;                   // Kruskal round convergence flag
  __shared__ double s_sum[16];             // block reduction staging
  __shared__ float s_max[16];
  __shared__ int s_cnt[16];

  unsigned long long* sbuf = pool;
  unsigned* hkey = (unsigned*)pool;
  unsigned* hval = hkey + NPIX;
  unsigned* key32 = (unsigned*)(pool + NPIX);
  unsigned short* label = (unsigned short*)(pool + NPIX + NPIX / 2);
  unsigned long long* node = pool + NPIX;

  const int blk = blockIdx.x;            // 24 blocks: b(4) x c(3) x pass(2)
  const int b = blk / 6;
  const int rem = blk % 6;
  const int c = (rem >> 1) + 1;          // classes 1..3
  const int pass = rem & 1;              // 0 = sublevel 8-conn (H0), 1 = superlevel 4-conn (H1)
  const float* img = x + (size_t)(b * 4 + c) * NPIX;
  const int tid = threadIdx.x;
  const int lane = tid & 63, wid = tid >> 6;
  const int ndirs = pass ? 4 : 8;
  const int drr[8] = {-1, 1, 0, 0, -1, -1, 1, 1};
  const int dcc[8] = { 0, 0,-1, 1, -1,  1, -1, 1};

  // --- phase 1: monotone keys (pass 1 negates); hash+claim init folded; min ---
  if (tid < 13) s_chg[tid] = 0;
  unsigned lmin = EMPTY;
  for (int i = tid; i < NPIX; i += NT) {
    float f = img[i];
    if (pass) f = -f;
    unsigned u = __float_as_uint(f);
    unsigned k = (u & 0x80000000u) ? ~u : (u | 0x80000000u);
    key32[i] = k;
    pool[i] = ~0ull;                     // hkey/hval = EMPTY (region [0,32K))
    claim[i] = 0;
    lmin = min(lmin, k);
  }
  for (int off = 32; off > 0; off >>= 1)
    lmin = min(lmin, (unsigned)__shfl_xor((int)lmin, off));
  if (lane == 0) wred[wid] = lmin;
  __syncthreads();
  unsigned vmink = (unsigned)wred[0];
  #pragma unroll
  for (int w = 1; w < 16; w++) vmink = min(vmink, (unsigned)wred[w]);

  // --- phase 2: watershed pointers + converging pointer jumping ---
  for (int i = tid; i < NPIX; i += NT) {
    unsigned long long best = ((unsigned long long)key32[i] << 32) | (unsigned)i;
    int bestnb = i;
    int r = i >> 6, cc = i & 63;
    for (int d = 0; d < ndirs; d++) {
      int rr = r + drr[d], c2 = cc + dcc[d];
      if ((unsigned)rr >= 64u || (unsigned)c2 >= 64u) continue;
      int nb = (rr << 6) | c2;
      unsigned long long pn = ((unsigned long long)key32[nb] << 32) | (unsigned)nb;
      if (pn < best) { best = pn; bestnb = nb; }
    }
    label[i] = (unsigned short)bestnb;
  }
  __syncthreads();
  for (int round = 0; round < 12; round++) {   // >= doubling per round; early exit
    bool changed = false;
    for (int i = tid; i < NPIX; i += NT) {
      unsigned short l = label[i];
      unsigned short l2 = label[l];
      if (l2 != l) { label[i] = l2; changed = true; }
    }
    if (changed) s_chg[round] = 1;
    __syncthreads();
    if (!s_chg[round]) break;                  // block-uniform
  }

  // --- phase 3: inter-basin edges deduped to min weight per basin pair ---
  const int pdr[4] = {1, 0, 1,  1};
  const int pdc[4] = {0, 1, 1, -1};
  const int npd = pass ? 2 : 4;
  for (int i = tid; i < NPIX; i += NT) {
    int r = i >> 6, cc = i & 63;
    unsigned la = label[i];
    unsigned ki = key32[i];
    for (int d = 0; d < npd; d++) {
      int rr = r + pdr[d], c2 = cc + pdc[d];
      if ((unsigned)rr >= 64u || (unsigned)c2 >= 64u) continue;
      int nb = (rr << 6) | c2;
      unsigned lb = label[nb];
      if (lb == la) continue;
      unsigned wkey = max(ki, key32[nb]);      // weight = max endpoint key
      unsigned pk = la < lb ? ((la << 12) | lb) : ((lb << 12) | la);
      unsigned h = (pk * 2654435761u) >> 20;
      while (true) {
        unsigned old = atomicCAS(&hkey[h], EMPTY, pk);
        if (old == EMPTY || old == pk) { atomicMin(&hval[h], wkey); break; }
        h = (h + 1) & (NPIX - 1);
      }
    }
  }
  __syncthreads();

  // --- phase 4: stage hash+keys+basin flags; ONE packed u64 scan (edges|basins);
  //     write edges, basin list, node records ---
  unsigned long long item[PPT];
  unsigned mykeys[PPT];
  int cnt = 0, bcnt = 0, bmask = 0;
  #pragma unroll
  for (int q = 0; q < PPT; q++) {
    int s = tid * PPT + q;
    unsigned pk = hkey[s];
    if (pk != EMPTY) item[cnt++] = (((unsigned long long)hval[s]) << 32) | pk;
  }
  #pragma unroll
  for (int t = 0; t < PPT; t++) {
    int i = tid + t * NT;
    mykeys[t] = key32[i];
    if (label[i] == (unsigned short)i) { bmask |= 1 << t; bcnt++; }
  }
  __syncthreads();                       // all reads of pool[0..56K) done
  unsigned long long inc2 = ((unsigned long long)cnt << 32) | (unsigned)bcnt;
  for (int off = 1; off < 64; off <<= 1) {   // intra-wave inclusive scan (both counts)
    unsigned long long v = __shfl_up(inc2, off);
    if (lane >= off) inc2 += v;
  }
  if (lane == 63) wred[wid] = inc2;
  __syncthreads();
  if (wid == 0) {                        // scan the 16 wave totals in wave 0
    unsigned long long wv = (lane < 16) ? wred[lane] : 0ull;
    for (int off = 1; off < 16; off <<= 1) {
      unsigned long long v = __shfl_up(wv, off);
      if (lane >= off) wv += v;
    }
    if (lane < 16) wred[16 + lane] = wv;
  }
  __syncthreads();
  const unsigned long long tot = wred[31];
  const int M = (int)(tot >> 32);
  const int NB = (int)(tot & 0xFFFFFFFFull);
  const unsigned long long wbase = (wid == 0) ? 0ull : wred[16 + wid - 1];
  const int base0 = (int)((wbase >> 32) + (inc2 >> 32)) - cnt;
  int bbase = (int)((wbase & 0xFFFFFFFFull) + (inc2 & 0xFFFFFFFFull)) - bcnt;
  __syncthreads();                       // wred consumed; pool writable
  for (int q = 0; q < cnt; q++) sbuf[base0 + q] = item[q];
  #pragma unroll
  for (int t = 0; t < PPT; t++) {
    int i = tid + t * NT;
    node[i] = (((unsigned long long)mykeys[t]) << 32) | (unsigned)i;  // singleton
    if (bmask & (1 << t)) blist[bbase++] = (unsigned short)i;
  }
  for (int i = M + tid; i < NPIX; i += NT) sbuf[i] = ~0ull;           // pad
  __syncthreads();

  // --- phase 5: sort edges ascending by weight key ---
  if (M <= 2048) {
    // Hybrid bitonic on 2048: j<64 via shfl_xor (no barrier); j in [64,512] via
    // ping-pong LDS (A=pool[0..2048), B=pool[2048..4096)); j=1024 in-thread.
    unsigned long long v0 = sbuf[tid];
    unsigned long long v1 = sbuf[tid + 1024];
    const int i0 = tid, i1 = tid + 1024;
    auto regstage = [&](int k, int j) {
      unsigned long long p0 = __shfl_xor(v0, j);
      unsigned long long p1 = __shfl_xor(v1, j);
      bool m0 = (((i0 & j) == 0) == ((i0 & k) == 0));
      bool m1 = (((i1 & j) == 0) == ((i1 & k) == 0));
      v0 = m0 ? (v0 < p0 ? v0 : p0) : (v0 > p0 ? v0 : p0);
      v1 = m1 ? (v1 < p1 ? v1 : p1) : (v1 > p1 ? v1 : p1);
    };
    int buf = 1;
    for (int k = 2; k <= 64; k <<= 1)
      for (int j = k >> 1; j >= 1; j >>= 1) regstage(k, j);
    for (int k = 128; k <= 2048; k <<= 1) {
      for (int j = k >> 1; j >= 64; j >>= 1) {
        if (j == 1024) {                 // partner is own other element; ascending
          if (v0 > v1) { unsigned long long t = v0; v0 = v1; v1 = t; }
        } else {
          unsigned long long* bp = pool + (buf ? 2048 : 0);
          bp[tid] = v0; bp[tid + 1024] = v1;
          __syncthreads();
          unsigned long long p0 = bp[tid ^ j];
          unsigned long long p1 = bp[(tid ^ j) + 1024];
          bool m0 = (((i0 & j) == 0) == ((i0 & k) == 0));
          bool m1 = (((i1 & j) == 0) == ((i1 & k) == 0));
          v0 = m0 ? (v0 < p0 ? v0 : p0) : (v0 > p0 ? v0 : p0);
          v1 = m1 ? (v1 < p1 ? v1 : p1) : (v1 > p1 ? v1 : p1);
          buf ^= 1;
        }
      }
      for (int j = 32; j >= 1; j >>= 1) regstage(k, j);
    }
    sbuf[tid] = v0; sbuf[tid + 1024] = v1;   // final: back to A for Kruskal
    __syncthreads();
  } else {
    // 4-elem/thread hybrid bitonic on all 4096 slots (4-conn pass can have
    // M in (2048,4096]): j<64 via shfl_xor; j in [64,512] via ping-pong LDS
    // (A=sbuf, B=sbuf2); j=1024/2048 in-thread.
    unsigned long long v0 = sbuf[tid];
    unsigned long long v1 = sbuf[tid + 1024];
    unsigned long long v2 = sbuf[tid + 2048];
    unsigned long long v3 = sbuf[tid + 3072];
    const int i0 = tid, i1 = tid + 1024, i2 = tid + 2048, i3 = tid + 3072;
    auto regstage4 = [&](int k, int j) {
      unsigned long long p0 = __shfl_xor(v0, j), p1 = __shfl_xor(v1, j);
      unsigned long long p2 = __shfl_xor(v2, j), p3 = __shfl_xor(v3, j);
      bool m0 = (((i0 & j) == 0) == ((i0 & k) == 0));
      bool m1 = (((i1 & j) == 0) == ((i1 & k) == 0));
      bool m2 = (((i2 & j) == 0) == ((i2 & k) == 0));
      bool m3 = (((i3 & j) == 0) == ((i3 & k) == 0));
      v0 = m0 ? (v0 < p0 ? v0 : p0) : (v0 > p0 ? v0 : p0);
      v1 = m1 ? (v1 < p1 ? v1 : p1) : (v1 > p1 ? v1 : p1);
      v2 = m2 ? (v2 < p2 ? v2 : p2) : (v2 > p2 ? v2 : p2);
      v3 = m3 ? (v3 < p3 ? v3 : p3) : (v3 > p3 ? v3 : p3);
    };
    auto ce2 = [&](unsigned long long &a, unsigned long long &bb2, int ia, int k) {
      bool up = ((ia & k) == 0);
      if ((a > bb2) == up) { unsigned long long t = a; a = bb2; bb2 = t; }
    };
    int buf = 1;
    auto ldsstage = [&](int k, int j) {
      unsigned long long* bp = buf ? sbuf2 : sbuf;
      bp[i0] = v0; bp[i1] = v1; bp[i2] = v2; bp[i3] = v3;
      __syncthreads();
      const int pt = tid ^ j;
      unsigned long long p0 = bp[pt], p1 = bp[pt + 1024];
      unsigned long long p2 = bp[pt + 2048], p3 = bp[pt + 3072];
      bool m0 = (((i0 & j) == 0) == ((i0 & k) == 0));
      bool m1 = (((i1 & j) == 0) == ((i1 & k) == 0));
      bool m2 = (((i2 & j) == 0) == ((i2 & k) == 0));
      bool m3 = (((i3 & j) == 0) == ((i3 & k) == 0));
      v0 = m0 ? (v0 < p0 ? v0 : p0) : (v0 > p0 ? v0 : p0);
      v1 = m1 ? (v1 < p1 ? v1 : p1) : (v1 > p1 ? v1 : p1);
      v2 = m2 ? (v2 < p2 ? v2 : p2) : (v2 > p2 ? v2 : p2);
      v3 = m3 ? (v3 < p3 ? v3 : p3) : (v3 > p3 ? v3 : p3);
      buf ^= 1;
    };
    for (int k = 2; k <= 64; k <<= 1)
      for (int j = k >> 1; j >= 1; j >>= 1) regstage4(k, j);
    for (int k = 128; k <= 4096; k <<= 1) {
      if (k == 4096) { ce2(v0, v2, i0, k); ce2(v1, v3, i1, k); }   // j = 2048
      if (k >= 2048) { ce2(v0, v1, i0, k); ce2(v2, v3, i2, k); }   // j = 1024
      for (int j = 512; j >= 64; j >>= 1) if (j < k) ldsstage(k, j);
      for (int j = 32; j >= 1; j >>= 1) regstage4(k, j);
    }
    __syncthreads();                     // last ldsstage readers done before A overwrite
    sbuf[i0] = v0; sbuf[i1] = v1; sbuf[i2] = v2; sbuf[i3] = v3;
    __syncthreads();
  }

  // --- phase 6: BLOCK-parallel Kruskal — CLAIM BOTH roots, TEST YOUNG only.
  //     Hazard fixed vs the young-only protocol: with creators cB>cA>cC and
  //     edges (A,B,w1)<(B,C,w2)<(A,C,w3), young-only lets (A,C) commit
  //     death(A)=w3 while (B,C) (which makes it a cycle) is still pending.
  //     Claiming BOTH roots makes the young-cell winner the minimum-weight
  //     in-flight edge incident on that component from EITHER side; since
  //     earlier batches are strictly lighter and done, that is exactly the
  //     sequential death condition: death(Y) = w(min edge leaving comp(Y)).
  //     Elder component creators only decrease, so the young choice and pair
  //     are order-invariant. Win-test ignores the elder cell, so shared-elder
  //     merges still commit in the same round (Boruvka-grade parallelism; no
  //     giant-component serialization). Rounds:
  //       r1 claim both -> B1 -> r2 young-win test+commit (+flag reset) ->
  //       B2 -> r4 re-find+vote -> B3 -> uniform exit check. ---
  double sumsq = 0.0;
  float maxp = 0.0f;
  int pcnt = 0;
  unsigned seq = 0;                      // block-uniform round counter (no claim resets)
  for (int ebase = 0; ebase < M; ebase += NT) {
    const int j = ebase + tid;
    const bool act = (j < M);
    unsigned long long e = act ? sbuf[j] : ~0ull;
    const unsigned wk = (unsigned)(e >> 32);
    const unsigned pk = (unsigned)(e & 0xFFFFFFu);
    unsigned xa = 0, xb = 0;
    unsigned long long recA = 0, recB = 0;
    bool pending = false;
    if (act) {
      xa = pk >> 12; xb = pk & 0xFFFu;
      recA = node[xa];
      recB = node[xb];                   // finds overlap across all 1024 threads
      while ((unsigned)recA != xa) { xa = (unsigned)recA; recA = node[xa]; }
      while ((unsigned)recB != xb) { xb = (unsigned)recB; recB = node[xb]; }
      pending = (xa != xb);
    }
    while (true) {
      seq++;                             // uniform: all threads execute the loop
      const unsigned myval = (seq << 10) | (unsigned)(NT - 1 - tid);
      unsigned t_elder = 0, t_young = 0;
      unsigned long long t_yrec = 0;
      // r1: claim BOTH roots (smaller tid = lighter edge = wins atomicMax)
      if (pending) {
        if (recA < recB) { t_elder = xa; t_young = xb; t_yrec = recB; }
        else             { t_elder = xb; t_young = xa; t_yrec = recA; }
        atomicMax(&claim[t_young], myval);
        atomicMax(&claim[t_elder], myval);
      }
      __syncthreads();                   // B1: all claims visible
      if (tid == 0) s_flag = 0;          // reset before any votes (post-B1, pre-B2)
      // r2: winner test on the YOUNG cell only + commit
      if (pending && claim[t_young] == myval) {
        const unsigned ky = (unsigned)(t_yrec >> 32);
        if (wk > ky) {                   // strictly positive persistence
          float pers = kval(wk) - kval(ky);
          sumsq += (double)pers * (double)pers;
          maxp = fmaxf(maxp, pers);
          pcnt++;
        }
        node[t_young] = (t_yrec & 0xFFFFFFFF00000000ull) | t_elder;
        pending = false;
      }
      __syncthreads();                   // B2: commits + flag reset visible
      // r4: losers re-find AFTER all commits of this round, then vote
      if (pending) {
        recA = node[xa]; recB = node[xb];
        while ((unsigned)recA != xa) { xa = (unsigned)recA; recA = node[xa]; }
        while ((unsigned)recB != xb) { xb = (unsigned)recB; recB = node[xb]; }
        pending = (xa != xb);
        if (pending) s_flag = 1;
      }
      __syncthreads();                   // B3: votes visible
      if (!s_flag) break;                // block-uniform
    }
    for (int i = tid; i < NB; i += NT) {     // flatten basins (NB <= 2048)
      const int p0 = blist[i];
      unsigned long long rec = node[p0];
      unsigned px = (unsigned)rec;
      if (px == (unsigned)p0) continue;
      unsigned long long r2 = node[px];
      while ((unsigned)r2 != px) { px = (unsigned)r2; r2 = node[px]; }
      node[p0] = (rec & 0xFFFFFFFF00000000ull) | px;
    }
    __syncthreads();
  }
  // block-wide reduction of (sumsq, maxp, pcnt): wave shfl then LDS combine
  for (int off = 32; off > 0; off >>= 1) {
    sumsq += __shfl_xor(sumsq, off);
    maxp = fmaxf(maxp, __shfl_xor(maxp, off));
    pcnt += __shfl_xor(pcnt, off);
  }
  if (lane == 0) { s_sum[wid] = sumsq; s_max[wid] = maxp; s_cnt[wid] = pcnt; }
  __syncthreads();

  // --- phase 7: per-block contribution ---
  float contrib = 0.0f;
  if (tid == 0) {
    #pragma unroll
    for (int w = 1; w < 16; w++) {
      sumsq += s_sum[w];
      maxp = fmaxf(maxp, s_max[w]);
      pcnt += s_cnt[w];
    }
    if (pass == 0) {
      const int nf0 = (c == 3) ? 2 : 1;      // TOPO H0: c1->1, c2->1, c3->2
      float vmin = kval(vmink);              // essential birth = global min
      if (nf0 == 1) {
        contrib = vmin * vmin + (float)sumsq;
      } else if (pcnt >= 1) {
        contrib = vmin * vmin + (1.0f - maxp) * (1.0f - maxp)
                + (float)(sumsq - (double)maxp * (double)maxp);
      } else {
        contrib = vmin * vmin + 1.0f;
      }
    } else {
      const int nf1 = (c == 2) ? 1 : 0;      // TOPO H1: c1->0, c2->1, c3->0
      if (nf1 == 0) contrib = (float)sumsq;
      else contrib = (pcnt >= 1)
        ? ((1.0f - maxp) * (1.0f - maxp) + (float)(sumsq - (double)maxp * (double)maxp))
        : 1.0f;
    }
    contrib *= 0.25f;                        // / B, B = 4
    if (use_ws) {
      // publish (value<<32 | magic) in one device-scope atomic — no fence needed
      atomicExch(&ws64[blk],
                 (((unsigned long long)__float_as_uint(contrib)) << 32) | FLAGMAGIC);
    } else {
      atomicAdd(out, contrib);               // out pre-zeroed by ph_zero_kernel
    }
  }
  // --- block 0 wave 0: gather all 24 contributions, write out ---
  if (use_ws && blk == 0 && wid == 0) {
    float v = 0.0f;
    if (lane < 24) {
      while (true) {
        unsigned long long r = atomicAdd(&ws64[lane], 0ull);  // device-coherent read
        if ((unsigned)r == FLAGMAGIC) { v = __uint_as_float((unsigned)(r >> 32)); break; }
      }
    }
    for (int off = 32; off > 0; off >>= 1) v += __shfl_xor(v, off);
    if (lane == 0) out[0] = v;
  }
}

extern "C" void kernel_launch(void* const* d_in, const int* in_sizes, int n_in,
                              void* d_out, int out_size, void* d_ws, size_t ws_size,
                              hipStream_t stream) {
  const float* x = (const float*)d_in[0];
  float* out = (float*)d_out;
  if (ws_size >= 24 * sizeof(unsigned long long)) {
    ph_pass_kernel<<<24, NT, 0, stream>>>(x, out, (unsigned long long*)d_ws, 1);
  } else {
    ph_zero_kernel<<<1, 1, 0, stream>>>(out);
    ph_pass_kernel<<<24, NT, 0, stream>>>(x, out, nullptr, 0);
  }
}

// Round 4
// 92.478 us; speedup vs baseline: 2.1850x; 1.2265x over previous
//
#include <hip/hip_runtime.h>

#define NPIX 4096
#define NT 1024
#define PPT (NPIX / NT)   // 4 per thread
#define EMPTY 0xFFFFFFFFu
#define FLAGMAGIC 0x00C0FFEEu

__global__ void ph_zero_kernel(float* out) { out[0] = 0.0f; }

__device__ __forceinline__ float kval(unsigned k) {
  unsigned u = (k & 0x80000000u) ? (k & 0x7FFFFFFFu) : ~k;
  return __uint_as_float(u);
}

__global__ __launch_bounds__(NT) void ph_pass_kernel(const float* __restrict__ x,
                                                     float* __restrict__ out,
                                                     unsigned long long* __restrict__ ws64,
                                                     int use_ws) {
  // One 64 KB pool, phase-aliased:
  //  [0,32K)  : hash (hkey 16K | hval 16K) -> compacted edge list (unsorted)
  //  [32K,48K): key32 u32[4096]            -> clobbered by node records
  //  [48K,56K): label u16[4096]            -> clobbered by node records
  //  [32K,64K): node u64[4096] = creatorKey<<32 | parent   (union-find phase)
  __shared__ unsigned long long pool[2 * NPIX];
  __shared__ unsigned long long claim64[NPIX]; // 32 KB seq-tagged claim cells
  __shared__ unsigned long long wred[32];  // wave staging: [0..15] raw, [16..31] scanned
  __shared__ int s_chg[13];                // watershed convergence flags
  __shared__ int s_flag;                   // union round convergence flag
  __shared__ double s_sum[16];             // block reduction staging
  __shared__ float s_max[16];
  __shared__ int s_cnt[16];

  unsigned long long* sbuf = pool;
  unsigned* hkey = (unsigned*)pool;
  unsigned* hval = hkey + NPIX;
  unsigned* key32 = (unsigned*)(pool + NPIX);
  unsigned short* label = (unsigned short*)(pool + NPIX + NPIX / 2);
  unsigned long long* node = pool + NPIX;

  const int blk = blockIdx.x;            // 24 blocks: b(4) x c(3) x pass(2)
  const int b = blk / 6;
  const int rem = blk % 6;
  const int c = (rem >> 1) + 1;          // classes 1..3
  const int pass = rem & 1;              // 0 = sublevel 8-conn (H0), 1 = superlevel 4-conn (H1)
  const float* img = x + (size_t)(b * 4 + c) * NPIX;
  const int tid = threadIdx.x;
  const int lane = tid & 63, wid = tid >> 6;
  const int ndirs = pass ? 4 : 8;
  const int drr[8] = {-1, 1, 0, 0, -1, -1, 1, 1};
  const int dcc[8] = { 0, 0,-1, 1, -1,  1, -1, 1};

  // --- phase 1: monotone keys (pass 1 negates); hash+claim init folded; min ---
  if (tid < 13) s_chg[tid] = 0;
  unsigned lmin = EMPTY;
  for (int i = tid; i < NPIX; i += NT) {
    float f = img[i];
    if (pass) f = -f;
    unsigned u = __float_as_uint(f);
    unsigned k = (u & 0x80000000u) ? ~u : (u | 0x80000000u);
    key32[i] = k;
    pool[i] = ~0ull;                     // hkey/hval = EMPTY (region [0,32K))
    claim64[i] = 0ull;                   // claims: any real claim (seq>=1) wins
    lmin = min(lmin, k);
  }
  for (int off = 32; off > 0; off >>= 1)
    lmin = min(lmin, (unsigned)__shfl_xor((int)lmin, off));
  if (lane == 0) wred[wid] = lmin;
  __syncthreads();
  unsigned vmink = (unsigned)wred[0];
  #pragma unroll
  for (int w = 1; w < 16; w++) vmink = min(vmink, (unsigned)wred[w]);

  // --- phase 2: watershed pointers + converging pointer jumping ---
  for (int i = tid; i < NPIX; i += NT) {
    unsigned long long best = ((unsigned long long)key32[i] << 32) | (unsigned)i;
    int bestnb = i;
    int r = i >> 6, cc = i & 63;
    for (int d = 0; d < ndirs; d++) {
      int rr = r + drr[d], c2 = cc + dcc[d];
      if ((unsigned)rr >= 64u || (unsigned)c2 >= 64u) continue;
      int nb = (rr << 6) | c2;
      unsigned long long pn = ((unsigned long long)key32[nb] << 32) | (unsigned)nb;
      if (pn < best) { best = pn; bestnb = nb; }
    }
    label[i] = (unsigned short)bestnb;
  }
  __syncthreads();
  for (int round = 0; round < 12; round++) {   // >= doubling per round; early exit
    bool changed = false;
    for (int i = tid; i < NPIX; i += NT) {
      unsigned short l = label[i];
      unsigned short l2 = label[l];
      if (l2 != l) { label[i] = l2; changed = true; }
    }
    if (changed) s_chg[round] = 1;
    __syncthreads();
    if (!s_chg[round]) break;                  // block-uniform
  }

  // --- phase 3: inter-basin edges deduped to min weight per basin pair ---
  const int pdr[4] = {1, 0, 1,  1};
  const int pdc[4] = {0, 1, 1, -1};
  const int npd = pass ? 2 : 4;
  for (int i = tid; i < NPIX; i += NT) {
    int r = i >> 6, cc = i & 63;
    unsigned la = label[i];
    unsigned ki = key32[i];
    for (int d = 0; d < npd; d++) {
      int rr = r + pdr[d], c2 = cc + pdc[d];
      if ((unsigned)rr >= 64u || (unsigned)c2 >= 64u) continue;
      int nb = (rr << 6) | c2;
      unsigned lb = label[nb];
      if (lb == la) continue;
      unsigned wkey = max(ki, key32[nb]);      // weight = max endpoint key
      unsigned pk = la < lb ? ((la << 12) | lb) : ((lb << 12) | la);
      unsigned h = (pk * 2654435761u) >> 20;
      while (true) {
        unsigned old = atomicCAS(&hkey[h], EMPTY, pk);
        if (old == EMPTY || old == pk) { atomicMin(&hval[h], wkey); break; }
        h = (h + 1) & (NPIX - 1);
      }
    }
  }
  __syncthreads();

  // --- phase 4: compact hash to an (unsorted) edge list; node records ---
  unsigned long long item[PPT];
  unsigned mykeys[PPT];
  int cnt = 0;
  #pragma unroll
  for (int q = 0; q < PPT; q++) {
    int s = tid * PPT + q;
    unsigned pk = hkey[s];
    if (pk != EMPTY) item[cnt++] = (((unsigned long long)hval[s]) << 32) | pk;
  }
  #pragma unroll
  for (int t = 0; t < PPT; t++) mykeys[t] = key32[tid + t * NT];
  __syncthreads();                       // all reads of pool[0..56K) done
  unsigned inc = (unsigned)cnt;
  for (int off = 1; off < 64; off <<= 1) {   // intra-wave inclusive scan
    unsigned v = __shfl_up(inc, off);
    if (lane >= off) inc += v;
  }
  if (lane == 63) wred[wid] = inc;
  __syncthreads();
  if (wid == 0) {                        // scan the 16 wave totals in wave 0
    unsigned wv = (lane < 16) ? (unsigned)wred[lane] : 0u;
    for (int off = 1; off < 16; off <<= 1) {
      unsigned v = __shfl_up(wv, off);
      if (lane >= off) wv += v;
    }
    if (lane < 16) wred[16 + lane] = wv;
  }
  __syncthreads();
  const int M = (int)wred[31];
  const int base0 = (int)((wid ? (unsigned)wred[16 + wid - 1] : 0u) + inc) - cnt;
  for (int q = 0; q < cnt; q++) sbuf[base0 + q] = item[q];
  #pragma unroll
  for (int t = 0; t < PPT; t++) {
    int i = tid + t * NT;
    node[i] = (((unsigned long long)mykeys[t]) << 32) | (unsigned)i;  // singleton
  }
  __syncthreads();

  // --- phase 6: ALL-AT-ONCE parallel Kruskal — no sort, no batches.
  //     Every edge in flight (4/thread); claim BOTH roots with priority
  //     (seq | ~weight | edge_id), winner test on the YOUNG cell only.
  //     Winner on cell Y = globally min remaining edge incident on comp(Y)
  //     (all incident edges claim Y) => death(Y) = that weight = sequential
  //     Kruskal. Lighter edges cannot join comp(Y) mid-round: any merge
  //     chain into comp(Y) has monotonically lighter winners toward Y, each
  //     claiming the next cell (claim-both), so invaders' weights >= wk(e).
  //     Global min pending edge always wins both cells => >=1 commit/round
  //     => terminates; ~Boruvka round count. Commit writes only node[young];
  //     creator fields are immutable; root cells never written by commits of
  //     other components => round snapshot reasoning holds across barriers:
  //       r1 claims -> B1 -> r2 young-win test+commit (+flag reset) -> B2 ->
  //       r4 re-find from cached roots + vote -> B3 -> uniform exit. ---
  double sumsq = 0.0;
  float maxp = 0.0f;
  int pcnt = 0;
  unsigned ewk[PPT], exa[PPT], exb[PPT];
  unsigned long long erA[PPT], erB[PPT];
  unsigned pmask = 0;
  #pragma unroll
  for (int q = 0; q < PPT; q++) {
    const int j = tid + q * NT;
    if (j < M) {
      const unsigned long long e = sbuf[j];
      ewk[q] = (unsigned)(e >> 32);
      const unsigned pk = (unsigned)(e & 0xFFFFFFu);
      unsigned xa = pk >> 12, xb = pk & 0xFFFu;   // basin roots (singletons now)
      unsigned long long recA = node[xa], recB = node[xb];
      while ((unsigned)recA != xa) { xa = (unsigned)recA; recA = node[xa]; }
      while ((unsigned)recB != xb) { xb = (unsigned)recB; recB = node[xb]; }
      exa[q] = xa; exb[q] = xb; erA[q] = recA; erB[q] = recB;
      if (xa != xb) pmask |= 1u << q;
    }
  }
  unsigned long long seqtag = 0;         // rounds << 44 (claims never reset)
  while (true) {
    seqtag += (1ull << 44);
    // r1: claim BOTH roots (priority: lighter weight, then larger edge id)
    #pragma unroll
    for (int q = 0; q < PPT; q++) {
      if (pmask & (1u << q)) {
        const int j = tid + q * NT;
        const unsigned long long myval =
            seqtag | (((unsigned long long)(~ewk[q])) << 12) | (unsigned)j;
        unsigned young, elder;
        if (erA[q] < erB[q]) { elder = exa[q]; young = exb[q]; }
        else                 { elder = exb[q]; young = exa[q]; }
        atomicMax(&claim64[young], myval);
        atomicMax(&claim64[elder], myval);
      }
    }
    __syncthreads();                     // B1: all claims visible
    if (tid == 0) s_flag = 0;            // reset before any votes
    // r2: winner test on the YOUNG cell only + commit
    #pragma unroll
    for (int q = 0; q < PPT; q++) {
      if (pmask & (1u << q)) {
        const int j = tid + q * NT;
        const unsigned long long myval =
            seqtag | (((unsigned long long)(~ewk[q])) << 12) | (unsigned)j;
        unsigned young, elder;
        unsigned long long yrec;
        if (erA[q] < erB[q]) { elder = exa[q]; young = exb[q]; yrec = erB[q]; }
        else                 { elder = exb[q]; young = exa[q]; yrec = erA[q]; }
        if (claim64[young] == myval) {
          const unsigned ky = (unsigned)(yrec >> 32);
          if (ewk[q] > ky) {             // strictly positive persistence
            float pers = kval(ewk[q]) - kval(ky);
            sumsq += (double)pers * (double)pers;
            maxp = fmaxf(maxp, pers);
            pcnt++;
          }
          node[young] = (yrec & 0xFFFFFFFF00000000ull) | elder;
          pmask &= ~(1u << q);
        }
      }
    }
    __syncthreads();                     // B2: commits + flag reset visible
    // r4: losers re-find from cached roots AFTER all commits, then vote
    bool any = false;
    #pragma unroll
    for (int q = 0; q < PPT; q++) {
      if (pmask & (1u << q)) {
        unsigned xa = exa[q], xb = exb[q];
        unsigned long long recA = node[xa], recB = node[xb];
        while ((unsigned)recA != xa) { xa = (unsigned)recA; recA = node[xa]; }
        while ((unsigned)recB != xb) { xb = (unsigned)recB; recB = node[xb]; }
        exa[q] = xa; exb[q] = xb; erA[q] = recA; erB[q] = recB;
        if (xa == xb) pmask &= ~(1u << q);   // became a cycle edge: drop
        else any = true;
      }
    }
    if (any) s_flag = 1;
    __syncthreads();                     // B3: votes visible
    if (!s_flag) break;                  // block-uniform
  }
  // block-wide reduction of (sumsq, maxp, pcnt): wave shfl then LDS combine
  for (int off = 32; off > 0; off >>= 1) {
    sumsq += __shfl_xor(sumsq, off);
    maxp = fmaxf(maxp, __shfl_xor(maxp, off));
    pcnt += __shfl_xor(pcnt, off);
  }
  if (lane == 0) { s_sum[wid] = sumsq; s_max[wid] = maxp; s_cnt[wid] = pcnt; }
  __syncthreads();

  // --- phase 7: per-block contribution ---
  float contrib = 0.0f;
  if (tid == 0) {
    #pragma unroll
    for (int w = 1; w < 16; w++) {
      sumsq += s_sum[w];
      maxp = fmaxf(maxp, s_max[w]);
      pcnt += s_cnt[w];
    }
    if (pass == 0) {
      const int nf0 = (c == 3) ? 2 : 1;      // TOPO H0: c1->1, c2->1, c3->2
      float vmin = kval(vmink);              // essential birth = global min
      if (nf0 == 1) {
        contrib = vmin * vmin + (float)sumsq;
      } else if (pcnt >= 1) {
        contrib = vmin * vmin + (1.0f - maxp) * (1.0f - maxp)
                + (float)(sumsq - (double)maxp * (double)maxp);
      } else {
        contrib = vmin * vmin + 1.0f;
      }
    } else {
      const int nf1 = (c == 2) ? 1 : 0;      // TOPO H1: c1->0, c2->1, c3->0
      if (nf1 == 0) contrib = (float)sumsq;
      else contrib = (pcnt >= 1)
        ? ((1.0f - maxp) * (1.0f - maxp) + (float)(sumsq - (double)maxp * (double)maxp))
        : 1.0f;
    }
    contrib *= 0.25f;                        // / B, B = 4
    if (use_ws) {
      // publish (value<<32 | magic) in one device-scope atomic — no fence needed
      atomicExch(&ws64[blk],
                 (((unsigned long long)__float_as_uint(contrib)) << 32) | FLAGMAGIC);
    } else {
      atomicAdd(out, contrib);               // out pre-zeroed by ph_zero_kernel
    }
  }
  // --- block 0 wave 0: gather all 24 contributions, write out ---
  if (use_ws && blk == 0 && wid == 0) {
    float v = 0.0f;
    if (lane < 24) {
      while (true) {
        unsigned long long r = atomicAdd(&ws64[lane], 0ull);  // device-coherent read
        if ((unsigned)r == FLAGMAGIC) { v = __uint_as_float((unsigned)(r >> 32)); break; }
      }
    }
    for (int off = 32; off > 0; off >>= 1) v += __shfl_xor(v, off);
    if (lane == 0) out[0] = v;
  }
}

extern "C" void kernel_launch(void* const* d_in, const int* in_sizes, int n_in,
                              void* d_out, int out_size, void* d_ws, size_t ws_size,
                              hipStream_t stream) {
  const float* x = (const float*)d_in[0];
  float* out = (float*)d_out;
  if (ws_size >= 24 * sizeof(unsigned long long)) {
    ph_pass_kernel<<<24, NT, 0, stream>>>(x, out, (unsigned long long*)d_ws, 1);
  } else {
    ph_zero_kernel<<<1, 1, 0, stream>>>(out);
    ph_pass_kernel<<<24, NT, 0, stream>>>(x, out, nullptr, 0);
  }
}